// Round 12
// baseline (1103.969 us; speedup 1.0000x reference)
//
#include <hip/hip_runtime.h>
#include <math.h>

// Problem constants (from setup_inputs)
#define N_NODES 4096
#define BATCH   32
#define D_EMB   10
#define CIN     2
#define COUT    64
#define CI      66          // CIN + COUT
#define KSUP    3
#define NCOLS   2112        // BATCH * CI
#define NPAD    2176        // NCOLS padded to 17*128 tiles
#define LDT     4096        // t-layout row stride (m contiguous)

// MFMA-transform constants
#define KI_REAL 198         // KSUP*CI
#define KILD    232         // LDS row stride for ki (>=224 for 7 ksteps; 232%32=8 -> conflict-safe)
#define OCH     (32 * KILD)    // 7424: entries per 32-output chunk
#define WROW_G  (128 * KILD)   // 29696 gate W entries per node
#define WROW_U  (64 * KILD)    // 14848 update W entries per node
#define WGT2_R  (WROW_G + WROW_U)  // 44544 ncols in the packed pool

typedef _Float16 half_t;
typedef __attribute__((ext_vector_type(8))) _Float16 f16x8;
typedef __attribute__((ext_vector_type(4))) _Float16 f16x4;
typedef __attribute__((ext_vector_type(2))) _Float16 f16x2;
typedef __attribute__((ext_vector_type(4))) float f32x4;

union u32h2 { unsigned u; f16x2 h; };

__device__ __forceinline__ float fast_sigmoid(float x) { return 1.f / (1.f + __expf(-x)); }
__device__ __forceinline__ float fast_tanh(float x) { return 1.f - 2.f / (__expf(2.f * x) + 1.f); }

__device__ __forceinline__ void gld_lds16(const half_t* g, half_t* l) {
  __builtin_amdgcn_global_load_lds(
      (const __attribute__((address_space(1))) void*)g,
      (__attribute__((address_space(3))) void*)l, 16, 0, 0);
}

// ---------------------------------------------------------------------------
// P[n,m] = softmax_m(relu(E[n,:].E[m,:])) stored directly as fp16.
// ---------------------------------------------------------------------------
__global__ __launch_bounds__(256) void k_softmax_p(const float* __restrict__ E,
                                                   half_t* __restrict__ Pb) {
  const int n = blockIdx.x;
  const int tid = threadIdx.x;
  __shared__ float En[D_EMB];
  __shared__ float ms[256], ss[256];
  if (tid < D_EMB) En[tid] = E[n * D_EMB + tid];
  __syncthreads();
  float en[D_EMB];
#pragma unroll
  for (int d = 0; d < D_EMB; ++d) en[d] = En[d];

  float m = -1e30f, s = 0.f;
  for (int c = tid; c < N_NODES; c += 256) {
    const float* Ec = E + c * D_EMB;
    float v = 0.f;
#pragma unroll
    for (int d = 0; d < D_EMB; ++d) v += en[d] * Ec[d];
    v = fmaxf(v, 0.f);
    if (v > m) { s *= __expf(m - v); m = v; }
    s += __expf(v - m);
  }
  ms[tid] = m; ss[tid] = s;
  __syncthreads();
  for (int off = 128; off > 0; off >>= 1) {
    if (tid < off) {
      float m2 = ms[tid + off], s2 = ss[tid + off];
      float m1 = ms[tid], s1 = ss[tid];
      float mm = fmaxf(m1, m2);
      ms[tid] = mm;
      ss[tid] = s1 * __expf(m1 - mm) + s2 * __expf(m2 - mm);
    }
    __syncthreads();
  }
  const float M = ms[0];
  const float inv = 1.f / ss[0];
  half_t* Pr = Pb + (size_t)n * N_NODES;
  for (int c = tid; c < N_NODES; c += 256) {
    const float* Ec = E + c * D_EMB;
    float v = 0.f;
#pragma unroll
    for (int d = 0; d < D_EMB; ++d) v += en[d] * Ec[d];
    v = fmaxf(v, 0.f);
    Pr[c] = (half_t)(__expf(v - M) * inv);
  }
}

// ---------------------------------------------------------------------------
// Build V0 in both layouts (+ X part of Cb in both layouts), fp16.
// ---------------------------------------------------------------------------
__global__ __launch_bounds__(256) void k_build_v0(const float* __restrict__ X,
                                                  const float* __restrict__ H,
                                                  half_t* __restrict__ Vt,
                                                  half_t* __restrict__ Vn,
                                                  half_t* __restrict__ Cbt,
                                                  half_t* __restrict__ Cbn) {
  size_t idx = (size_t)blockIdx.x * 256 + threadIdx.x;
  if (idx >= (size_t)N_NODES * NCOLS) return;
  const int m = (int)(idx / NCOLS);
  const int col = (int)(idx % NCOLS);
  const int b = col / CI;
  const int c = col % CI;
  float v;
  if (c < CIN) v = X[((size_t)b * N_NODES + m) * CIN + c];
  else         v = H[((size_t)b * N_NODES + m) * COUT + (c - CIN)];
  const half_t h = (half_t)v;
  Vn[(size_t)m * NPAD + col] = h;
  Vt[(size_t)col * LDT + m] = h;
  if (c < CIN) {
    Cbn[(size_t)m * NPAD + col] = h;
    Cbt[(size_t)col * LDT + m] = h;
  }
}

// ---------------------------------------------------------------------------
// fp16 MFMA NT-GEMM: C[m][n] = sum_k A[m][k] * Bt[n][k]
// K-MAJOR LDS chunk numbering (R11 change): staging lane l fetches
// (row = l&15, kgroup = l>>4), so LDS region layout is chunk = kg*16 + row15.
// Fragment reads then sweep 16 consecutive 16B chunks per 16-lane group ->
// bank-conflict-free (was 8-way aliased with row-major chunks).
// ---------------------------------------------------------------------------
__global__ __launch_bounds__(256) void k_gemm_f16(const half_t* __restrict__ A,
                                                  const half_t* __restrict__ Bt,
                                                  half_t* __restrict__ Cn,
                                                  half_t* __restrict__ Ct) {
  __shared__ half_t As[128 * 32];
  __shared__ half_t Bs[128 * 32];
  const int tid = threadIdx.x;
  const int lane = tid & 63;
  const int wave = tid >> 6;
  const int wm = (wave >> 1) * 64;
  const int wn = (wave & 1) * 64;
  const int rb = blockIdx.y * 128;
  const int cb = blockIdx.x * 128;

  // k-major staging: lane l -> row (l&15), k-group (l>>4)*8
  const int srow = (lane & 15);
  const int skg = (lane >> 4) * 8;
  const half_t* ga0 = A + (size_t)(rb + wave * 32 + srow) * N_NODES + skg;
  const half_t* ga1 = ga0 + (size_t)16 * N_NODES;
  const half_t* gb0 = Bt + (size_t)(cb + wave * 32 + srow) * LDT + skg;
  const half_t* gb1 = gb0 + (size_t)16 * LDT;
  half_t* lA0 = As + wave * 1024;    // region 2*wave (512 halves each)
  half_t* lA1 = lA0 + 512;           // region 2*wave+1
  half_t* lB0 = Bs + wave * 1024;
  half_t* lB1 = lB0 + 512;

  const int fr = lane & 15;
  const int fk = (lane >> 4) * 8;
  // within-region half offset for fragment (row&15 = fr, kgroup = fk/8):
  // chunk = (fk/8)*16 + fr, 8 halves/chunk -> offset = fk*16 + fr*8
  const int fofs = fk * 16 + fr * 8;

  f32x4 acc[4][4] = {};

  for (int k0 = 0; k0 < N_NODES; k0 += 32) {
    __syncthreads();
    gld_lds16(ga0 + k0, lA0);
    gld_lds16(ga1 + k0, lA1);
    gld_lds16(gb0 + k0, lB0);
    gld_lds16(gb1 + k0, lB1);
    __syncthreads();

    f16x8 a[4], b[4];
#pragma unroll
    for (int i = 0; i < 4; ++i)
      a[i] = *(const f16x8*)&As[((wm >> 4) + i) * 512 + fofs];
#pragma unroll
    for (int j = 0; j < 4; ++j)
      b[j] = *(const f16x8*)&Bs[((wn >> 4) + j) * 512 + fofs];
#pragma unroll
    for (int i = 0; i < 4; ++i)
#pragma unroll
      for (int j = 0; j < 4; ++j)
        acc[i][j] = __builtin_amdgcn_mfma_f32_16x16x32_f16(a[i], b[j], acc[i][j], 0, 0, 0);
  }

  const int en = lane & 15;
  const int em = (lane >> 4) * 4;
#pragma unroll
  for (int i = 0; i < 4; ++i) {
#pragma unroll
    for (int j = 0; j < 4; ++j) {
      const int m0 = rb + wm + i * 16 + em;
      const int n = cb + wn + j * 16 + en;
      half_t h0 = (half_t)acc[i][j][0];
      half_t h1 = (half_t)acc[i][j][1];
      half_t h2 = (half_t)acc[i][j][2];
      half_t h3 = (half_t)acc[i][j][3];
      if (Ct) {
        f16x4 t4 = {h0, h1, h2, h3};
        *(f16x4*)&Ct[(size_t)n * LDT + m0] = t4;
      }
      Cn[(size_t)(m0 + 0) * NPAD + n] = h0;
      Cn[(size_t)(m0 + 1) * NPAD + n] = h1;
      Cn[(size_t)(m0 + 2) * NPAD + n] = h2;
      Cn[(size_t)(m0 + 3) * NPAD + n] = h3;
    }
  }
}

// ---------------------------------------------------------------------------
// WT2: d-pair-packed fp16 pool, L2-resident.
// ---------------------------------------------------------------------------
__global__ __launch_bounds__(256) void k_wgt2(const float* __restrict__ Wg,
                                              const float* __restrict__ Wu,
                                              unsigned* __restrict__ WT2) {
  const int r = blockIdx.x * 256 + threadIdx.x;
  if (r >= WGT2_R) return;
  const float* pool;
  int o, ki, ostr;
  if (r < WROW_G) { o = r / KILD; ki = r % KILD; pool = Wg; ostr = 128; }
  else { int r2 = r - WROW_G; o = r2 / KILD; ki = r2 % KILD; pool = Wu; ostr = 64; }
#pragma unroll
  for (int dp = 0; dp < 5; ++dp) {
    u32h2 v; v.h = f16x2{(half_t)0.f, (half_t)0.f};
    if (ki < KI_REAL) {
      const int k = ki / CI;
      const int i = ki % CI;
      v.h[0] = (half_t)pool[(((size_t)(2 * dp) * KSUP + k) * CI + i) * ostr + o];
      v.h[1] = (half_t)pool[(((size_t)(2 * dp + 1) * KSUP + k) * CI + i) * ostr + o];
    }
    WT2[(size_t)dp * WGT2_R + r] = v.u;
  }
}

// ---------------------------------------------------------------------------
// Shared helper: stage xg for one node into LDS (rows b=0..31, ki-padded).
// ---------------------------------------------------------------------------
__device__ __forceinline__ void stage_xg(const half_t* __restrict__ v0r,
                                         const half_t* __restrict__ g1r,
                                         const half_t* __restrict__ g2r,
                                         half_t* __restrict__ xg, int tid) {
  for (int idx = tid; idx < NCOLS / 8; idx += 256) {
    const f16x8 v0 = *(const f16x8*)&v0r[idx * 8];
    const f16x8 g1 = *(const f16x8*)&g1r[idx * 8];
    const f16x8 g2 = *(const f16x8*)&g2r[idx * 8];
    const f16x8 x2 = g2 + g2 - v0;
#pragma unroll
    for (int e = 0; e < 8; ++e) {
      const int col = idx * 8 + e;
      const int b = col / CI;
      const int i = col - b * CI;
      xg[b * KILD + i] = v0[e];
      xg[b * KILD + CI + i] = g1[e];
      xg[b * KILD + 2 * CI + i] = x2[e];
    }
  }
  for (int z = tid; z < 32 * 17; z += 256) {
    const int b = z / 17;
    const int j = z - b * 17;
    *(unsigned*)&xg[b * KILD + KI_REAL + j * 2] = 0u;
  }
}

// ---------------------------------------------------------------------------
// Gate transform: block = 2 nodes, 4 output-chunks of 32 time-multiplexed.
// WT2 octets read once per node-PAIR. (R10-proven)
// ---------------------------------------------------------------------------
__global__ __launch_bounds__(256) void k_gate_t(const half_t* __restrict__ Vn,
                                                const half_t* __restrict__ G1n,
                                                const half_t* __restrict__ G2n,
                                                const unsigned* __restrict__ WT2,
                                                const float* __restrict__ E,
                                                const float* __restrict__ bg,
                                                const float* __restrict__ H,
                                                half_t* __restrict__ Cbn,
                                                half_t* __restrict__ Cbt,
                                                half_t* __restrict__ Rb) {
  const int n0 = blockIdx.x * 2;
  const int tid = threadIdx.x;
  const int lane = tid & 63;
  const int wave = tid >> 6;
  __shared__ half_t Wl[2][OCH];
  __shared__ half_t xg[2][OCH];
  __shared__ float biasl[2][128];

  f16x2 e2p0[5], e2p1[5];
#pragma unroll
  for (int dp = 0; dp < 5; ++dp) {
    e2p0[dp][0] = (half_t)E[n0 * D_EMB + 2 * dp];
    e2p0[dp][1] = (half_t)E[n0 * D_EMB + 2 * dp + 1];
    e2p1[dp][0] = (half_t)E[(n0 + 1) * D_EMB + 2 * dp];
    e2p1[dp][1] = (half_t)E[(n0 + 1) * D_EMB + 2 * dp + 1];
  }

  {
    const int nn = tid >> 7;
    const int o = tid & 127;
    float s = 0.f;
#pragma unroll
    for (int d = 0; d < D_EMB; ++d) s += E[(n0 + nn) * D_EMB + d] * bg[d * 128 + o];
    biasl[nn][o] = s;
  }
  stage_xg(Vn + (size_t)n0 * NPAD, G1n + (size_t)n0 * NPAD, G2n + (size_t)n0 * NPAD, xg[0], tid);
  stage_xg(Vn + (size_t)(n0 + 1) * NPAD, G1n + (size_t)(n0 + 1) * NPAD, G2n + (size_t)(n0 + 1) * NPAD, xg[1], tid);

  const int fr = lane & 15;
  const int fk = (lane >> 4) * 8;
  const int en = lane & 15;
  const int em = (lane >> 4) * 4;
  const int node = wave & 1;
  const int ot = wave >> 1;
  const int nn = n0 + node;

#pragma unroll
  for (int p = 0; p < 4; ++p) {
    if (p > 0) __syncthreads();
    for (int base = tid * 8; base < OCH; base += 2048) {
      float a0[8] = {}, a1[8] = {};
#pragma unroll
      for (int dp = 0; dp < 5; ++dp) {
        const unsigned* wrow = WT2 + (size_t)dp * WGT2_R + p * OCH + base;
        uint4 wa = *(const uint4*)wrow;
        uint4 wb = *(const uint4*)(wrow + 4);
        u32h2 c0, c1, c2, c3;
        c0.u = wa.x; c1.u = wa.y; c2.u = wa.z; c3.u = wa.w;
        a0[0] = __builtin_amdgcn_fdot2(c0.h, e2p0[dp], a0[0], false);
        a0[1] = __builtin_amdgcn_fdot2(c1.h, e2p0[dp], a0[1], false);
        a0[2] = __builtin_amdgcn_fdot2(c2.h, e2p0[dp], a0[2], false);
        a0[3] = __builtin_amdgcn_fdot2(c3.h, e2p0[dp], a0[3], false);
        a1[0] = __builtin_amdgcn_fdot2(c0.h, e2p1[dp], a1[0], false);
        a1[1] = __builtin_amdgcn_fdot2(c1.h, e2p1[dp], a1[1], false);
        a1[2] = __builtin_amdgcn_fdot2(c2.h, e2p1[dp], a1[2], false);
        a1[3] = __builtin_amdgcn_fdot2(c3.h, e2p1[dp], a1[3], false);
        c0.u = wb.x; c1.u = wb.y; c2.u = wb.z; c3.u = wb.w;
        a0[4] = __builtin_amdgcn_fdot2(c0.h, e2p0[dp], a0[4], false);
        a0[5] = __builtin_amdgcn_fdot2(c1.h, e2p0[dp], a0[5], false);
        a0[6] = __builtin_amdgcn_fdot2(c2.h, e2p0[dp], a0[6], false);
        a0[7] = __builtin_amdgcn_fdot2(c3.h, e2p0[dp], a0[7], false);
        a1[4] = __builtin_amdgcn_fdot2(c0.h, e2p1[dp], a1[4], false);
        a1[5] = __builtin_amdgcn_fdot2(c1.h, e2p1[dp], a1[5], false);
        a1[6] = __builtin_amdgcn_fdot2(c2.h, e2p1[dp], a1[6], false);
        a1[7] = __builtin_amdgcn_fdot2(c3.h, e2p1[dp], a1[7], false);
      }
      f16x8 w0, w1;
#pragma unroll
      for (int e = 0; e < 8; ++e) { w0[e] = (half_t)a0[e]; w1[e] = (half_t)a1[e]; }
      *(f16x8*)&Wl[0][base] = w0;
      *(f16x8*)&Wl[1][base] = w1;
    }
    __syncthreads();

    f32x4 acc2[2] = {};
#pragma unroll
    for (int ks = 0; ks < 7; ++ks) {
      const f16x8 a0 = *(const f16x8*)&xg[node][fr * KILD + ks * 32 + fk];
      const f16x8 a1 = *(const f16x8*)&xg[node][(16 + fr) * KILD + ks * 32 + fk];
      const f16x8 b0 = *(const f16x8*)&Wl[node][(ot * 16 + fr) * KILD + ks * 32 + fk];
      acc2[0] = __builtin_amdgcn_mfma_f32_16x16x32_f16(a0, b0, acc2[0], 0, 0, 0);
      acc2[1] = __builtin_amdgcn_mfma_f32_16x16x32_f16(a1, b0, acc2[1], 0, 0, 0);
    }
    const int o_g = p * 32 + ot * 16 + en;
    const float bo = biasl[node][o_g];
#pragma unroll
    for (int i = 0; i < 2; ++i)
#pragma unroll
      for (int r = 0; r < 4; ++r) {
        const int b = i * 16 + em + r;
        const float s = fast_sigmoid(acc2[i][r] + bo);
        if (p < 2) {
          const float hv = H[((size_t)b * N_NODES + nn) * COUT + o_g];
          const half_t z = (half_t)(s * hv);
          const int c0 = b * CI + CIN + o_g;
          Cbn[(size_t)nn * NPAD + c0] = z;
          Cbt[(size_t)c0 * LDT + nn] = z;
        } else {
          Rb[((size_t)b * N_NODES + nn) * COUT + (o_g - 64)] = (half_t)s;
        }
      }
  }
}

// ---------------------------------------------------------------------------
// Update transform: block = 2 nodes, 2 output-chunks of 32, WT2 shared.
// ---------------------------------------------------------------------------
__global__ __launch_bounds__(256) void k_update_t(const half_t* __restrict__ Cbn,
                                                  const half_t* __restrict__ G1n,
                                                  const half_t* __restrict__ G2n,
                                                  const unsigned* __restrict__ WT2,
                                                  const float* __restrict__ E,
                                                  const float* __restrict__ bu,
                                                  const float* __restrict__ H,
                                                  const half_t* __restrict__ Rb,
                                                  float* __restrict__ Out) {
  const int n0 = blockIdx.x * 2;
  const int tid = threadIdx.x;
  const int lane = tid & 63;
  const int wave = tid >> 6;
  __shared__ half_t Wl[2][OCH];
  __shared__ half_t xg[2][OCH];
  __shared__ float biasl[2][64];

  f16x2 e2p0[5], e2p1[5];
#pragma unroll
  for (int dp = 0; dp < 5; ++dp) {
    e2p0[dp][0] = (half_t)E[n0 * D_EMB + 2 * dp];
    e2p0[dp][1] = (half_t)E[n0 * D_EMB + 2 * dp + 1];
    e2p1[dp][0] = (half_t)E[(n0 + 1) * D_EMB + 2 * dp];
    e2p1[dp][1] = (half_t)E[(n0 + 1) * D_EMB + 2 * dp + 1];
  }

  if (tid < 128) {
    const int nn = tid >> 6;
    const int o = tid & 63;
    float s = 0.f;
#pragma unroll
    for (int d = 0; d < D_EMB; ++d) s += E[(n0 + nn) * D_EMB + d] * bu[d * COUT + o];
    biasl[nn][o] = s;
  }
  stage_xg(Cbn + (size_t)n0 * NPAD, G1n + (size_t)n0 * NPAD, G2n + (size_t)n0 * NPAD, xg[0], tid);
  stage_xg(Cbn + (size_t)(n0 + 1) * NPAD, G1n + (size_t)(n0 + 1) * NPAD, G2n + (size_t)(n0 + 1) * NPAD, xg[1], tid);

  const int fr = lane & 15;
  const int fk = (lane >> 4) * 8;
  const int en = lane & 15;
  const int em = (lane >> 4) * 4;
  const int node = wave & 1;
  const int ot = wave >> 1;
  const int nn = n0 + node;

#pragma unroll
  for (int p = 0; p < 2; ++p) {
    if (p > 0) __syncthreads();
    for (int base = tid * 8; base < OCH; base += 2048) {
      float a0[8] = {}, a1[8] = {};
#pragma unroll
      for (int dp = 0; dp < 5; ++dp) {
        const unsigned* wrow = WT2 + (size_t)dp * WGT2_R + WROW_G + p * OCH + base;
        uint4 wa = *(const uint4*)wrow;
        uint4 wb = *(const uint4*)(wrow + 4);
        u32h2 c0, c1, c2, c3;
        c0.u = wa.x; c1.u = wa.y; c2.u = wa.z; c3.u = wa.w;
        a0[0] = __builtin_amdgcn_fdot2(c0.h, e2p0[dp], a0[0], false);
        a0[1] = __builtin_amdgcn_fdot2(c1.h, e2p0[dp], a0[1], false);
        a0[2] = __builtin_amdgcn_fdot2(c2.h, e2p0[dp], a0[2], false);
        a0[3] = __builtin_amdgcn_fdot2(c3.h, e2p0[dp], a0[3], false);
        a1[0] = __builtin_amdgcn_fdot2(c0.h, e2p1[dp], a1[0], false);
        a1[1] = __builtin_amdgcn_fdot2(c1.h, e2p1[dp], a1[1], false);
        a1[2] = __builtin_amdgcn_fdot2(c2.h, e2p1[dp], a1[2], false);
        a1[3] = __builtin_amdgcn_fdot2(c3.h, e2p1[dp], a1[3], false);
        c0.u = wb.x; c1.u = wb.y; c2.u = wb.z; c3.u = wb.w;
        a0[4] = __builtin_amdgcn_fdot2(c0.h, e2p0[dp], a0[4], false);
        a0[5] = __builtin_amdgcn_fdot2(c1.h, e2p0[dp], a0[5], false);
        a0[6] = __builtin_amdgcn_fdot2(c2.h, e2p0[dp], a0[6], false);
        a0[7] = __builtin_amdgcn_fdot2(c3.h, e2p0[dp], a0[7], false);
        a1[4] = __builtin_amdgcn_fdot2(c0.h, e2p1[dp], a1[4], false);
        a1[5] = __builtin_amdgcn_fdot2(c1.h, e2p1[dp], a1[5], false);
        a1[6] = __builtin_amdgcn_fdot2(c2.h, e2p1[dp], a1[6], false);
        a1[7] = __builtin_amdgcn_fdot2(c3.h, e2p1[dp], a1[7], false);
      }
      f16x8 w0, w1;
#pragma unroll
      for (int e = 0; e < 8; ++e) { w0[e] = (half_t)a0[e]; w1[e] = (half_t)a1[e]; }
      *(f16x8*)&Wl[0][base] = w0;
      *(f16x8*)&Wl[1][base] = w1;
    }
    __syncthreads();

    f32x4 acc2[2] = {};
#pragma unroll
    for (int ks = 0; ks < 7; ++ks) {
      const f16x8 a0 = *(const f16x8*)&xg[node][fr * KILD + ks * 32 + fk];
      const f16x8 a1 = *(const f16x8*)&xg[node][(16 + fr) * KILD + ks * 32 + fk];
      const f16x8 b0 = *(const f16x8*)&Wl[node][(ot * 16 + fr) * KILD + ks * 32 + fk];
      acc2[0] = __builtin_amdgcn_mfma_f32_16x16x32_f16(a0, b0, acc2[0], 0, 0, 0);
      acc2[1] = __builtin_amdgcn_mfma_f32_16x16x32_f16(a1, b0, acc2[1], 0, 0, 0);
    }
    const int o = p * 32 + ot * 16 + en;
    const float bo = biasl[node][o];
#pragma unroll
    for (int i = 0; i < 2; ++i)
#pragma unroll
      for (int r = 0; r < 4; ++r) {
        const int b = i * 16 + em + r;
        const float hc = fast_tanh(acc2[i][r] + bo);
        const size_t base = ((size_t)b * N_NODES + nn) * COUT + o;
        const float hv = H[base];
        const float rr = (float)Rb[base];
        Out[base] = rr * hv + (1.f - rr) * hc;
      }
  }
}

// ---------------------------------------------------------------------------
extern "C" void kernel_launch(void* const* d_in, const int* in_sizes, int n_in,
                              void* d_out, int out_size, void* d_ws, size_t ws_size,
                              hipStream_t stream) {
  const float* X  = (const float*)d_in[0];
  const float* H  = (const float*)d_in[1];
  const float* E  = (const float*)d_in[2];
  const float* Wg = (const float*)d_in[3];
  const float* bg = (const float*)d_in[4];
  const float* Wu = (const float*)d_in[5];
  const float* bu = (const float*)d_in[6];
  float* out = (float*)d_out;

  const size_t SZ_P = (size_t)N_NODES * N_NODES;
  const size_t SZ_M = (size_t)NPAD * LDT;
  half_t* Pb  = (half_t*)d_ws;
  half_t* Vt  = Pb + SZ_P;
  half_t* Vn  = Vt + SZ_M;
  half_t* G1t = Vn + SZ_M;
  half_t* G1n = G1t + SZ_M;
  half_t* G2n = G1n + SZ_M;
  half_t* Cbt = G2n + SZ_M;
  half_t* Cbn = Cbt + SZ_M;
  half_t* Rb  = Cbn + SZ_M;
  unsigned* WT2 = (unsigned*)(Rb + (size_t)BATCH * N_NODES * COUT);

  // 1. adjacency + inputs + packed pool
  k_softmax_p<<<N_NODES, 256, 0, stream>>>(E, Pb);
  {
    const size_t tot = (size_t)N_NODES * NCOLS;
    k_build_v0<<<(int)((tot + 255) / 256), 256, 0, stream>>>(X, H, Vt, Vn, Cbt, Cbn);
  }
  k_wgt2<<<(WGT2_R + 255) / 256, 256, 0, stream>>>(Wg, Wu, WT2);

  dim3 gg(NPAD / 128, N_NODES / 128);
  // 2. gate propagation + transform
  k_gemm_f16<<<gg, 256, 0, stream>>>(Pb, Vt, G1n, G1t);
  k_gemm_f16<<<gg, 256, 0, stream>>>(Pb, G1t, G2n, nullptr);
  k_gate_t<<<N_NODES / 2, 256, 0, stream>>>(Vn, G1n, G2n, WT2, E, bg, H, Cbn, Cbt, Rb);
  // 3. update propagation + transform + output
  k_gemm_f16<<<gg, 256, 0, stream>>>(Pb, Cbt, G1n, G1t);
  k_gemm_f16<<<gg, 256, 0, stream>>>(Pb, G1t, G2n, nullptr);
  k_update_t<<<N_NODES / 2, 256, 0, stream>>>(Cbn, G1n, G2n, WT2, E, bu, H, Rb, out);
}

// Round 13
// 823.520 us; speedup vs baseline: 1.3405x; 1.3405x over previous
//
#include <hip/hip_runtime.h>
#include <math.h>

// Problem constants (from setup_inputs)
#define N_NODES 4096
#define BATCH   32
#define D_EMB   10
#define CIN     2
#define COUT    64
#define CI      66          // CIN + COUT
#define KSUP    3
#define NCOLS   2112        // BATCH * CI
#define NPAD    2176        // NCOLS padded to 17*128 tiles
#define LDT     4096        // t-layout row stride (m contiguous)

// MFMA-transform constants
#define KI_REAL 198         // KSUP*CI
#define KILD    232         // LDS row stride for ki (>=224 for 7 ksteps; 232%32=8 -> conflict-safe)
#define OCH     (32 * KILD)    // 7424: entries per 32-output chunk
#define WROW_G  (128 * KILD)   // 29696 gate W entries per node
#define WROW_U  (64 * KILD)    // 14848 update W entries per node
#define WGT2_R  (WROW_G + WROW_U)  // 44544 ncols in the packed pool

typedef _Float16 half_t;
typedef __attribute__((ext_vector_type(8))) _Float16 f16x8;
typedef __attribute__((ext_vector_type(4))) _Float16 f16x4;
typedef __attribute__((ext_vector_type(2))) _Float16 f16x2;
typedef __attribute__((ext_vector_type(4))) float f32x4;

union u32h2 { unsigned u; f16x2 h; };

__device__ __forceinline__ float fast_sigmoid(float x) { return 1.f / (1.f + __expf(-x)); }
__device__ __forceinline__ float fast_tanh(float x) { return 1.f - 2.f / (__expf(2.f * x) + 1.f); }

__device__ __forceinline__ void gld_lds16(const half_t* g, half_t* l) {
  __builtin_amdgcn_global_load_lds(
      (const __attribute__((address_space(1))) void*)g,
      (__attribute__((address_space(3))) void*)l, 16, 0, 0);
}

// ---------------------------------------------------------------------------
// P[n,m] = softmax_m(relu(E[n,:].E[m,:])) stored directly as fp16.
// ---------------------------------------------------------------------------
__global__ __launch_bounds__(256) void k_softmax_p(const float* __restrict__ E,
                                                   half_t* __restrict__ Pb) {
  const int n = blockIdx.x;
  const int tid = threadIdx.x;
  __shared__ float En[D_EMB];
  __shared__ float ms[256], ss[256];
  if (tid < D_EMB) En[tid] = E[n * D_EMB + tid];
  __syncthreads();
  float en[D_EMB];
#pragma unroll
  for (int d = 0; d < D_EMB; ++d) en[d] = En[d];

  float m = -1e30f, s = 0.f;
  for (int c = tid; c < N_NODES; c += 256) {
    const float* Ec = E + c * D_EMB;
    float v = 0.f;
#pragma unroll
    for (int d = 0; d < D_EMB; ++d) v += en[d] * Ec[d];
    v = fmaxf(v, 0.f);
    if (v > m) { s *= __expf(m - v); m = v; }
    s += __expf(v - m);
  }
  ms[tid] = m; ss[tid] = s;
  __syncthreads();
  for (int off = 128; off > 0; off >>= 1) {
    if (tid < off) {
      float m2 = ms[tid + off], s2 = ss[tid + off];
      float m1 = ms[tid], s1 = ss[tid];
      float mm = fmaxf(m1, m2);
      ms[tid] = mm;
      ss[tid] = s1 * __expf(m1 - mm) + s2 * __expf(m2 - mm);
    }
    __syncthreads();
  }
  const float M = ms[0];
  const float inv = 1.f / ss[0];
  half_t* Pr = Pb + (size_t)n * N_NODES;
  for (int c = tid; c < N_NODES; c += 256) {
    const float* Ec = E + c * D_EMB;
    float v = 0.f;
#pragma unroll
    for (int d = 0; d < D_EMB; ++d) v += en[d] * Ec[d];
    v = fmaxf(v, 0.f);
    Pr[c] = (half_t)(__expf(v - M) * inv);
  }
}

// ---------------------------------------------------------------------------
// Build V0 in both layouts (+ X part of Cb in both layouts), fp16.
// ---------------------------------------------------------------------------
__global__ __launch_bounds__(256) void k_build_v0(const float* __restrict__ X,
                                                  const float* __restrict__ H,
                                                  half_t* __restrict__ Vt,
                                                  half_t* __restrict__ Vn,
                                                  half_t* __restrict__ Cbt,
                                                  half_t* __restrict__ Cbn) {
  size_t idx = (size_t)blockIdx.x * 256 + threadIdx.x;
  if (idx >= (size_t)N_NODES * NCOLS) return;
  const int m = (int)(idx / NCOLS);
  const int col = (int)(idx % NCOLS);
  const int b = col / CI;
  const int c = col % CI;
  float v;
  if (c < CIN) v = X[((size_t)b * N_NODES + m) * CIN + c];
  else         v = H[((size_t)b * N_NODES + m) * COUT + (c - CIN)];
  const half_t h = (half_t)v;
  Vn[(size_t)m * NPAD + col] = h;
  Vt[(size_t)col * LDT + m] = h;
  if (c < CIN) {
    Cbn[(size_t)m * NPAD + col] = h;
    Cbt[(size_t)col * LDT + m] = h;
  }
}

// ---------------------------------------------------------------------------
// fp16 MFMA NT-GEMM: C[m][n] = sum_k A[m][k] * Bt[n][k]
// R13 staging swizzle: lane s fetches (row = s>>2, kg = ((s&3)+((s>>3)&3))&3).
//  - 4-lane groups still cover one 64B row segment (coalescing preserved;
//    in-segment permutation is merged by the coalescer).
//  - Fragment (row r, kgroup g) lives in chunk 4r + ((g-(r>>1))&3): each
//    aligned 8-lane phase hits 8 distinct bank-groups -> conflict-free.
// (R11's chunk=4r+g: 8-way conflicts, 8.9e6. R12's k-major: conflict-free but
//  scattered 16B global txns, +60% dur. This map satisfies both constraints.)
// ---------------------------------------------------------------------------
__global__ __launch_bounds__(256) void k_gemm_f16(const half_t* __restrict__ A,
                                                  const half_t* __restrict__ Bt,
                                                  half_t* __restrict__ Cn,
                                                  half_t* __restrict__ Ct) {
  __shared__ half_t As[128 * 32];
  __shared__ half_t Bs[128 * 32];
  const int tid = threadIdx.x;
  const int lane = tid & 63;
  const int wave = tid >> 6;
  const int wm = (wave >> 1) * 64;
  const int wn = (wave & 1) * 64;
  const int rb = blockIdx.y * 128;
  const int cb = blockIdx.x * 128;

  // swizzled staging
  const int srow = lane >> 2;
  const int skg = (((lane & 3) + ((lane >> 3) & 3)) & 3) * 8;
  const half_t* ga0 = A + (size_t)(rb + wave * 32 + srow) * N_NODES + skg;
  const half_t* ga1 = ga0 + (size_t)16 * N_NODES;
  const half_t* gb0 = Bt + (size_t)(cb + wave * 32 + srow) * LDT + skg;
  const half_t* gb1 = gb0 + (size_t)16 * LDT;
  half_t* lA0 = As + wave * 1024;    // region 2*wave (512 halves = 64 chunks)
  half_t* lA1 = lA0 + 512;
  half_t* lB0 = Bs + wave * 1024;
  half_t* lB1 = lB0 + 512;

  const int fr = lane & 15;
  const int fg = lane >> 4;          // kgroup 0..3
  // fragment (row fr, kgroup fg) -> chunk 4*fr + ((fg - (fr>>1)) & 3)
  const int fofs = (4 * fr + ((fg - (fr >> 1)) & 3)) * 8;

  f32x4 acc[4][4] = {};

  for (int k0 = 0; k0 < N_NODES; k0 += 32) {
    __syncthreads();
    gld_lds16(ga0 + k0, lA0);
    gld_lds16(ga1 + k0, lA1);
    gld_lds16(gb0 + k0, lB0);
    gld_lds16(gb1 + k0, lB1);
    __syncthreads();

    f16x8 a[4], b[4];
#pragma unroll
    for (int i = 0; i < 4; ++i)
      a[i] = *(const f16x8*)&As[((wm >> 4) + i) * 512 + fofs];
#pragma unroll
    for (int j = 0; j < 4; ++j)
      b[j] = *(const f16x8*)&Bs[((wn >> 4) + j) * 512 + fofs];
#pragma unroll
    for (int i = 0; i < 4; ++i)
#pragma unroll
      for (int j = 0; j < 4; ++j)
        acc[i][j] = __builtin_amdgcn_mfma_f32_16x16x32_f16(a[i], b[j], acc[i][j], 0, 0, 0);
  }

  const int en = lane & 15;
  const int em = (lane >> 4) * 4;
#pragma unroll
  for (int i = 0; i < 4; ++i) {
#pragma unroll
    for (int j = 0; j < 4; ++j) {
      const int m0 = rb + wm + i * 16 + em;
      const int n = cb + wn + j * 16 + en;
      half_t h0 = (half_t)acc[i][j][0];
      half_t h1 = (half_t)acc[i][j][1];
      half_t h2 = (half_t)acc[i][j][2];
      half_t h3 = (half_t)acc[i][j][3];
      if (Ct) {
        f16x4 t4 = {h0, h1, h2, h3};
        *(f16x4*)&Ct[(size_t)n * LDT + m0] = t4;
      }
      Cn[(size_t)(m0 + 0) * NPAD + n] = h0;
      Cn[(size_t)(m0 + 1) * NPAD + n] = h1;
      Cn[(size_t)(m0 + 2) * NPAD + n] = h2;
      Cn[(size_t)(m0 + 3) * NPAD + n] = h3;
    }
  }
}

// ---------------------------------------------------------------------------
// WT2: d-pair-packed fp16 pool, L2-resident.
// ---------------------------------------------------------------------------
__global__ __launch_bounds__(256) void k_wgt2(const float* __restrict__ Wg,
                                              const float* __restrict__ Wu,
                                              unsigned* __restrict__ WT2) {
  const int r = blockIdx.x * 256 + threadIdx.x;
  if (r >= WGT2_R) return;
  const float* pool;
  int o, ki, ostr;
  if (r < WROW_G) { o = r / KILD; ki = r % KILD; pool = Wg; ostr = 128; }
  else { int r2 = r - WROW_G; o = r2 / KILD; ki = r2 % KILD; pool = Wu; ostr = 64; }
#pragma unroll
  for (int dp = 0; dp < 5; ++dp) {
    u32h2 v; v.h = f16x2{(half_t)0.f, (half_t)0.f};
    if (ki < KI_REAL) {
      const int k = ki / CI;
      const int i = ki % CI;
      v.h[0] = (half_t)pool[(((size_t)(2 * dp) * KSUP + k) * CI + i) * ostr + o];
      v.h[1] = (half_t)pool[(((size_t)(2 * dp + 1) * KSUP + k) * CI + i) * ostr + o];
    }
    WT2[(size_t)dp * WGT2_R + r] = v.u;
  }
}

// ---------------------------------------------------------------------------
// Shared helper: stage xg for one node into LDS (rows b=0..31, ki-padded).
// ---------------------------------------------------------------------------
__device__ __forceinline__ void stage_xg(const half_t* __restrict__ v0r,
                                         const half_t* __restrict__ g1r,
                                         const half_t* __restrict__ g2r,
                                         half_t* __restrict__ xg, int tid) {
  for (int idx = tid; idx < NCOLS / 8; idx += 256) {
    const f16x8 v0 = *(const f16x8*)&v0r[idx * 8];
    const f16x8 g1 = *(const f16x8*)&g1r[idx * 8];
    const f16x8 g2 = *(const f16x8*)&g2r[idx * 8];
    const f16x8 x2 = g2 + g2 - v0;
#pragma unroll
    for (int e = 0; e < 8; ++e) {
      const int col = idx * 8 + e;
      const int b = col / CI;
      const int i = col - b * CI;
      xg[b * KILD + i] = v0[e];
      xg[b * KILD + CI + i] = g1[e];
      xg[b * KILD + 2 * CI + i] = x2[e];
    }
  }
  for (int z = tid; z < 32 * 17; z += 256) {
    const int b = z / 17;
    const int j = z - b * 17;
    *(unsigned*)&xg[b * KILD + KI_REAL + j * 2] = 0u;
  }
}

// ---------------------------------------------------------------------------
// Gate transform: block = 2 nodes, 4 output-chunks of 32 time-multiplexed.
// WT2 octets read once per node-PAIR. (R10/R11-proven)
// ---------------------------------------------------------------------------
__global__ __launch_bounds__(256) void k_gate_t(const half_t* __restrict__ Vn,
                                                const half_t* __restrict__ G1n,
                                                const half_t* __restrict__ G2n,
                                                const unsigned* __restrict__ WT2,
                                                const float* __restrict__ E,
                                                const float* __restrict__ bg,
                                                const float* __restrict__ H,
                                                half_t* __restrict__ Cbn,
                                                half_t* __restrict__ Cbt,
                                                half_t* __restrict__ Rb) {
  const int n0 = blockIdx.x * 2;
  const int tid = threadIdx.x;
  const int lane = tid & 63;
  const int wave = tid >> 6;
  __shared__ half_t Wl[2][OCH];
  __shared__ half_t xg[2][OCH];
  __shared__ float biasl[2][128];

  f16x2 e2p0[5], e2p1[5];
#pragma unroll
  for (int dp = 0; dp < 5; ++dp) {
    e2p0[dp][0] = (half_t)E[n0 * D_EMB + 2 * dp];
    e2p0[dp][1] = (half_t)E[n0 * D_EMB + 2 * dp + 1];
    e2p1[dp][0] = (half_t)E[(n0 + 1) * D_EMB + 2 * dp];
    e2p1[dp][1] = (half_t)E[(n0 + 1) * D_EMB + 2 * dp + 1];
  }

  {
    const int nn = tid >> 7;
    const int o = tid & 127;
    float s = 0.f;
#pragma unroll
    for (int d = 0; d < D_EMB; ++d) s += E[(n0 + nn) * D_EMB + d] * bg[d * 128 + o];
    biasl[nn][o] = s;
  }
  stage_xg(Vn + (size_t)n0 * NPAD, G1n + (size_t)n0 * NPAD, G2n + (size_t)n0 * NPAD, xg[0], tid);
  stage_xg(Vn + (size_t)(n0 + 1) * NPAD, G1n + (size_t)(n0 + 1) * NPAD, G2n + (size_t)(n0 + 1) * NPAD, xg[1], tid);

  const int fr = lane & 15;
  const int fk = (lane >> 4) * 8;
  const int en = lane & 15;
  const int em = (lane >> 4) * 4;
  const int node = wave & 1;
  const int ot = wave >> 1;
  const int nn = n0 + node;

#pragma unroll
  for (int p = 0; p < 4; ++p) {
    if (p > 0) __syncthreads();
    for (int base = tid * 8; base < OCH; base += 2048) {
      float a0[8] = {}, a1[8] = {};
#pragma unroll
      for (int dp = 0; dp < 5; ++dp) {
        const unsigned* wrow = WT2 + (size_t)dp * WGT2_R + p * OCH + base;
        uint4 wa = *(const uint4*)wrow;
        uint4 wb = *(const uint4*)(wrow + 4);
        u32h2 c0, c1, c2, c3;
        c0.u = wa.x; c1.u = wa.y; c2.u = wa.z; c3.u = wa.w;
        a0[0] = __builtin_amdgcn_fdot2(c0.h, e2p0[dp], a0[0], false);
        a0[1] = __builtin_amdgcn_fdot2(c1.h, e2p0[dp], a0[1], false);
        a0[2] = __builtin_amdgcn_fdot2(c2.h, e2p0[dp], a0[2], false);
        a0[3] = __builtin_amdgcn_fdot2(c3.h, e2p0[dp], a0[3], false);
        a1[0] = __builtin_amdgcn_fdot2(c0.h, e2p1[dp], a1[0], false);
        a1[1] = __builtin_amdgcn_fdot2(c1.h, e2p1[dp], a1[1], false);
        a1[2] = __builtin_amdgcn_fdot2(c2.h, e2p1[dp], a1[2], false);
        a1[3] = __builtin_amdgcn_fdot2(c3.h, e2p1[dp], a1[3], false);
        c0.u = wb.x; c1.u = wb.y; c2.u = wb.z; c3.u = wb.w;
        a0[4] = __builtin_amdgcn_fdot2(c0.h, e2p0[dp], a0[4], false);
        a0[5] = __builtin_amdgcn_fdot2(c1.h, e2p0[dp], a0[5], false);
        a0[6] = __builtin_amdgcn_fdot2(c2.h, e2p0[dp], a0[6], false);
        a0[7] = __builtin_amdgcn_fdot2(c3.h, e2p0[dp], a0[7], false);
        a1[4] = __builtin_amdgcn_fdot2(c0.h, e2p1[dp], a1[4], false);
        a1[5] = __builtin_amdgcn_fdot2(c1.h, e2p1[dp], a1[5], false);
        a1[6] = __builtin_amdgcn_fdot2(c2.h, e2p1[dp], a1[6], false);
        a1[7] = __builtin_amdgcn_fdot2(c3.h, e2p1[dp], a1[7], false);
      }
      f16x8 w0, w1;
#pragma unroll
      for (int e = 0; e < 8; ++e) { w0[e] = (half_t)a0[e]; w1[e] = (half_t)a1[e]; }
      *(f16x8*)&Wl[0][base] = w0;
      *(f16x8*)&Wl[1][base] = w1;
    }
    __syncthreads();

    f32x4 acc2[2] = {};
#pragma unroll
    for (int ks = 0; ks < 7; ++ks) {
      const f16x8 a0 = *(const f16x8*)&xg[node][fr * KILD + ks * 32 + fk];
      const f16x8 a1 = *(const f16x8*)&xg[node][(16 + fr) * KILD + ks * 32 + fk];
      const f16x8 b0 = *(const f16x8*)&Wl[node][(ot * 16 + fr) * KILD + ks * 32 + fk];
      acc2[0] = __builtin_amdgcn_mfma_f32_16x16x32_f16(a0, b0, acc2[0], 0, 0, 0);
      acc2[1] = __builtin_amdgcn_mfma_f32_16x16x32_f16(a1, b0, acc2[1], 0, 0, 0);
    }
    const int o_g = p * 32 + ot * 16 + en;
    const float bo = biasl[node][o_g];
#pragma unroll
    for (int i = 0; i < 2; ++i)
#pragma unroll
      for (int r = 0; r < 4; ++r) {
        const int b = i * 16 + em + r;
        const float s = fast_sigmoid(acc2[i][r] + bo);
        if (p < 2) {
          const float hv = H[((size_t)b * N_NODES + nn) * COUT + o_g];
          const half_t z = (half_t)(s * hv);
          const int c0 = b * CI + CIN + o_g;
          Cbn[(size_t)nn * NPAD + c0] = z;
          Cbt[(size_t)c0 * LDT + nn] = z;
        } else {
          Rb[((size_t)b * N_NODES + nn) * COUT + (o_g - 64)] = (half_t)s;
        }
      }
  }
}

// ---------------------------------------------------------------------------
// Update transform: block = 2 nodes, 2 output-chunks of 32, WT2 shared.
// ---------------------------------------------------------------------------
__global__ __launch_bounds__(256) void k_update_t(const half_t* __restrict__ Cbn,
                                                  const half_t* __restrict__ G1n,
                                                  const half_t* __restrict__ G2n,
                                                  const unsigned* __restrict__ WT2,
                                                  const float* __restrict__ E,
                                                  const float* __restrict__ bu,
                                                  const float* __restrict__ H,
                                                  const half_t* __restrict__ Rb,
                                                  float* __restrict__ Out) {
  const int n0 = blockIdx.x * 2;
  const int tid = threadIdx.x;
  const int lane = tid & 63;
  const int wave = tid >> 6;
  __shared__ half_t Wl[2][OCH];
  __shared__ half_t xg[2][OCH];
  __shared__ float biasl[2][64];

  f16x2 e2p0[5], e2p1[5];
#pragma unroll
  for (int dp = 0; dp < 5; ++dp) {
    e2p0[dp][0] = (half_t)E[n0 * D_EMB + 2 * dp];
    e2p0[dp][1] = (half_t)E[n0 * D_EMB + 2 * dp + 1];
    e2p1[dp][0] = (half_t)E[(n0 + 1) * D_EMB + 2 * dp];
    e2p1[dp][1] = (half_t)E[(n0 + 1) * D_EMB + 2 * dp + 1];
  }

  if (tid < 128) {
    const int nn = tid >> 6;
    const int o = tid & 63;
    float s = 0.f;
#pragma unroll
    for (int d = 0; d < D_EMB; ++d) s += E[(n0 + nn) * D_EMB + d] * bu[d * COUT + o];
    biasl[nn][o] = s;
  }
  stage_xg(Cbn + (size_t)n0 * NPAD, G1n + (size_t)n0 * NPAD, G2n + (size_t)n0 * NPAD, xg[0], tid);
  stage_xg(Cbn + (size_t)(n0 + 1) * NPAD, G1n + (size_t)(n0 + 1) * NPAD, G2n + (size_t)(n0 + 1) * NPAD, xg[1], tid);

  const int fr = lane & 15;
  const int fk = (lane >> 4) * 8;
  const int en = lane & 15;
  const int em = (lane >> 4) * 4;
  const int node = wave & 1;
  const int ot = wave >> 1;
  const int nn = n0 + node;

#pragma unroll
  for (int p = 0; p < 2; ++p) {
    if (p > 0) __syncthreads();
    for (int base = tid * 8; base < OCH; base += 2048) {
      float a0[8] = {}, a1[8] = {};
#pragma unroll
      for (int dp = 0; dp < 5; ++dp) {
        const unsigned* wrow = WT2 + (size_t)dp * WGT2_R + WROW_G + p * OCH + base;
        uint4 wa = *(const uint4*)wrow;
        uint4 wb = *(const uint4*)(wrow + 4);
        u32h2 c0, c1, c2, c3;
        c0.u = wa.x; c1.u = wa.y; c2.u = wa.z; c3.u = wa.w;
        a0[0] = __builtin_amdgcn_fdot2(c0.h, e2p0[dp], a0[0], false);
        a0[1] = __builtin_amdgcn_fdot2(c1.h, e2p0[dp], a0[1], false);
        a0[2] = __builtin_amdgcn_fdot2(c2.h, e2p0[dp], a0[2], false);
        a0[3] = __builtin_amdgcn_fdot2(c3.h, e2p0[dp], a0[3], false);
        a1[0] = __builtin_amdgcn_fdot2(c0.h, e2p1[dp], a1[0], false);
        a1[1] = __builtin_amdgcn_fdot2(c1.h, e2p1[dp], a1[1], false);
        a1[2] = __builtin_amdgcn_fdot2(c2.h, e2p1[dp], a1[2], false);
        a1[3] = __builtin_amdgcn_fdot2(c3.h, e2p1[dp], a1[3], false);
        c0.u = wb.x; c1.u = wb.y; c2.u = wb.z; c3.u = wb.w;
        a0[4] = __builtin_amdgcn_fdot2(c0.h, e2p0[dp], a0[4], false);
        a0[5] = __builtin_amdgcn_fdot2(c1.h, e2p0[dp], a0[5], false);
        a0[6] = __builtin_amdgcn_fdot2(c2.h, e2p0[dp], a0[6], false);
        a0[7] = __builtin_amdgcn_fdot2(c3.h, e2p0[dp], a0[7], false);
        a1[4] = __builtin_amdgcn_fdot2(c0.h, e2p1[dp], a1[4], false);
        a1[5] = __builtin_amdgcn_fdot2(c1.h, e2p1[dp], a1[5], false);
        a1[6] = __builtin_amdgcn_fdot2(c2.h, e2p1[dp], a1[6], false);
        a1[7] = __builtin_amdgcn_fdot2(c3.h, e2p1[dp], a1[7], false);
      }
      f16x8 w0, w1;
#pragma unroll
      for (int e = 0; e < 8; ++e) { w0[e] = (half_t)a0[e]; w1[e] = (half_t)a1[e]; }
      *(f16x8*)&Wl[0][base] = w0;
      *(f16x8*)&Wl[1][base] = w1;
    }
    __syncthreads();

    f32x4 acc2[2] = {};
#pragma unroll
    for (int ks = 0; ks < 7; ++ks) {
      const f16x8 a0 = *(const f16x8*)&xg[node][fr * KILD + ks * 32 + fk];
      const f16x8 a1 = *(const f16x8*)&xg[node][(16 + fr) * KILD + ks * 32 + fk];
      const f16x8 b0 = *(const f16x8*)&Wl[node][(ot * 16 + fr) * KILD + ks * 32 + fk];
      acc2[0] = __builtin_amdgcn_mfma_f32_16x16x32_f16(a0, b0, acc2[0], 0, 0, 0);
      acc2[1] = __builtin_amdgcn_mfma_f32_16x16x32_f16(a1, b0, acc2[1], 0, 0, 0);
    }
    const int o = p * 32 + ot * 16 + en;
    const float bo = biasl[node][o];
#pragma unroll
    for (int i = 0; i < 2; ++i)
#pragma unroll
      for (int r = 0; r < 4; ++r) {
        const int b = i * 16 + em + r;
        const float hc = fast_tanh(acc2[i][r] + bo);
        const size_t base = ((size_t)b * N_NODES + nn) * COUT + o;
        const float hv = H[base];
        const float rr = (float)Rb[base];
        Out[base] = rr * hv + (1.f - rr) * hc;
      }
  }
}

// ---------------------------------------------------------------------------
extern "C" void kernel_launch(void* const* d_in, const int* in_sizes, int n_in,
                              void* d_out, int out_size, void* d_ws, size_t ws_size,
                              hipStream_t stream) {
  const float* X  = (const float*)d_in[0];
  const float* H  = (const float*)d_in[1];
  const float* E  = (const float*)d_in[2];
  const float* Wg = (const float*)d_in[3];
  const float* bg = (const float*)d_in[4];
  const float* Wu = (const float*)d_in[5];
  const float* bu = (const float*)d_in[6];
  float* out = (float*)d_out;

  const size_t SZ_P = (size_t)N_NODES * N_NODES;
  const size_t SZ_M = (size_t)NPAD * LDT;
  half_t* Pb  = (half_t*)d_ws;
  half_t* Vt  = Pb + SZ_P;
  half_t* Vn  = Vt + SZ_M;
  half_t* G1t = Vn + SZ_M;
  half_t* G1n = G1t + SZ_M;
  half_t* G2n = G1n + SZ_M;
  half_t* Cbt = G2n + SZ_M;
  half_t* Cbn = Cbt + SZ_M;
  half_t* Rb  = Cbn + SZ_M;
  unsigned* WT2 = (unsigned*)(Rb + (size_t)BATCH * N_NODES * COUT);

  // 1. adjacency + inputs + packed pool
  k_softmax_p<<<N_NODES, 256, 0, stream>>>(E, Pb);
  {
    const size_t tot = (size_t)N_NODES * NCOLS;
    k_build_v0<<<(int)((tot + 255) / 256), 256, 0, stream>>>(X, H, Vt, Vn, Cbt, Cbn);
  }
  k_wgt2<<<(WGT2_R + 255) / 256, 256, 0, stream>>>(Wg, Wu, WT2);

  dim3 gg(NPAD / 128, N_NODES / 128);
  // 2. gate propagation + transform
  k_gemm_f16<<<gg, 256, 0, stream>>>(Pb, Vt, G1n, G1t);
  k_gemm_f16<<<gg, 256, 0, stream>>>(Pb, G1t, G2n, nullptr);
  k_gate_t<<<N_NODES / 2, 256, 0, stream>>>(Vn, G1n, G2n, WT2, E, bg, H, Cbn, Cbt, Rb);
  // 3. update propagation + transform + output
  k_gemm_f16<<<gg, 256, 0, stream>>>(Pb, Cbt, G1n, G1t);
  k_gemm_f16<<<gg, 256, 0, stream>>>(Pb, G1t, G2n, nullptr);
  k_update_t<<<N_NODES / 2, 256, 0, stream>>>(Cbn, G1n, G2n, WT2, E, bu, H, Rb, out);
}